// Round 1
// baseline (763.364 us; speedup 1.0000x reference)
//
#include <hip/hip_runtime.h>

// ---------------------------------------------------------------------------
// CausalSelfAttention on MI355X (gfx950), bf16 MFMA pipeline.
// Shapes: B=4, T=2048, C=2048, H=16, D=128. N_qkv=6144.
// d_out = [ out f32 (B,T,C) | k f32 (B,H,T,D) | v f32 (B,H,T,D) ]
// ---------------------------------------------------------------------------

typedef __attribute__((ext_vector_type(4))) float f32x4;
typedef __attribute__((ext_vector_type(8))) __bf16 bf16x8;
typedef __attribute__((ext_vector_type(4))) unsigned short us4;

__device__ __forceinline__ unsigned short f2bf(float f) {
  unsigned u = __float_as_uint(f);
  u += 0x7FFFu + ((u >> 16) & 1u);   // round-to-nearest-even
  return (unsigned short)(u >> 16);
}

__device__ __forceinline__ void gl_lds16(const void* g, void* l) {
  // async global->LDS, 16B per lane; LDS dest must be uniform-base + lane*16
  __builtin_amdgcn_global_load_lds(
      (const __attribute__((address_space(1))) void*)g,
      (__attribute__((address_space(3))) void*)l, 16, 0, 0);
}

__device__ __forceinline__ f32x4 mfma_bf16(bf16x8 a, bf16x8 b, f32x4 c) {
  return __builtin_amdgcn_mfma_f32_16x16x32_bf16(a, b, c, 0, 0, 0);
}

// ---------------------------------------------------------------------------
// Prep kernels
// ---------------------------------------------------------------------------

// RoPE table: cos/sin[t][i], t in [0,2048), i in [0,64)
__global__ __launch_bounds__(256) void rope_table_kernel(float* __restrict__ cos_t,
                                                         float* __restrict__ sin_t) {
  int idx = blockIdx.x * 256 + threadIdx.x;   // 131072 entries
  int t = idx >> 6, i = idx & 63;
  // inv_freq = 10000^(-i/64) = exp(-i * ln(10000)/64)
  float freq = __expf(-(float)i * 0.14391156831212787f);
  float ang = (float)t * freq;
  float s, c;
  sincosf(ang, &s, &c);
  cos_t[idx] = c;
  sin_t[idx] = s;
}

// fp32 -> bf16 flat convert (vectorized)
__global__ __launch_bounds__(256) void conv_bf16_kernel(const float* __restrict__ in,
                                                        unsigned short* __restrict__ out,
                                                        int n4) {
  int idx = blockIdx.x * 256 + threadIdx.x;
  int stride = gridDim.x * 256;
  for (; idx < n4; idx += stride) {
    float4 v = ((const float4*)in)[idx];
    us4 o;
    o[0] = f2bf(v.x); o[1] = f2bf(v.y); o[2] = f2bf(v.z); o[3] = f2bf(v.w);
    ((us4*)out)[idx] = o;
  }
}

// W [R][C] f32  ->  Wt [C][R] bf16  (tiled 64x64 via LDS, coalesced both sides)
__global__ __launch_bounds__(256) void transpose_conv_kernel(const float* __restrict__ in,
                                                             unsigned short* __restrict__ out,
                                                             int R, int C) {
  __shared__ unsigned short tile[64][68];
  const int t = threadIdx.x;
  const int c0 = blockIdx.x * 64, r0 = blockIdx.y * 64;
  const int cq = t & 15, rr = t >> 4;
#pragma unroll
  for (int i = 0; i < 4; ++i) {
    int r = rr + i * 16;
    float4 v = *(const float4*)&in[(size_t)(r0 + r) * C + c0 + cq * 4];
    tile[r][cq * 4 + 0] = f2bf(v.x);
    tile[r][cq * 4 + 1] = f2bf(v.y);
    tile[r][cq * 4 + 2] = f2bf(v.z);
    tile[r][cq * 4 + 3] = f2bf(v.w);
  }
  __syncthreads();
#pragma unroll
  for (int ii = 0; ii < 4; ++ii) {
    int c = rr + ii * 16;
    us4 o;
#pragma unroll
    for (int jj = 0; jj < 4; ++jj) o[jj] = tile[cq * 4 + jj][c];
    *(us4*)&out[(size_t)(c0 + c) * R + r0 + cq * 4] = o;
  }
}

// v f32 [z][T][D] -> vt bf16 [z][D][T]   (z = B*H = 64)
__global__ __launch_bounds__(256) void vtrans_kernel(const float* __restrict__ in,
                                                     unsigned short* __restrict__ out) {
  __shared__ unsigned short tile[64][68];
  const int t = threadIdx.x;
  const int t0 = blockIdx.x * 64;   // token tile
  const int d0 = blockIdx.y * 64;   // dim tile
  const size_t zi = (size_t)blockIdx.z * 2048 * 128;
  const size_t zo = (size_t)blockIdx.z * 128 * 2048;
  const int cq = t & 15, rr = t >> 4;
#pragma unroll
  for (int i = 0; i < 4; ++i) {
    int r = rr + i * 16;
    float4 v = *(const float4*)&in[zi + (size_t)(t0 + r) * 128 + d0 + cq * 4];
    tile[r][cq * 4 + 0] = f2bf(v.x);
    tile[r][cq * 4 + 1] = f2bf(v.y);
    tile[r][cq * 4 + 2] = f2bf(v.z);
    tile[r][cq * 4 + 3] = f2bf(v.w);
  }
  __syncthreads();
#pragma unroll
  for (int ii = 0; ii < 4; ++ii) {
    int c = rr + ii * 16;
    us4 o;
#pragma unroll
    for (int jj = 0; jj < 4; ++jj) o[jj] = tile[cq * 4 + jj][c];
    *(us4*)&out[zo + (size_t)(d0 + c) * 2048 + t0 + cq * 4] = o;
  }
}

// ---------------------------------------------------------------------------
// GEMM1: qkv = x @ W_attn + b_attn, fused RoPE epilogue.
// A = xbf [8192][2048], B = wt [6144][2048] (pre-transposed), 128x128 tile BK=64.
// 4 waves, each 32 rows x 128 cols (full head -> RoPE pairs are lane-local).
// ---------------------------------------------------------------------------
__global__ __launch_bounds__(256) void gemm_qkv_kernel(
    const unsigned short* __restrict__ xbf, const unsigned short* __restrict__ wt,
    const float* __restrict__ bias, const float* __restrict__ cost,
    const float* __restrict__ sint, float* __restrict__ out_k,
    float* __restrict__ out_v, unsigned short* __restrict__ qbf,
    unsigned short* __restrict__ kbf) {
  __shared__ __attribute__((aligned(16))) unsigned short As[128 * 64];
  __shared__ __attribute__((aligned(16))) unsigned short Bs[128 * 64];
  const int tid = threadIdx.x;
  const int w = tid >> 6, l = tid & 63, g = l >> 4, ln = l & 15;
  const int m0 = blockIdx.x * 128;
  const int nb = blockIdx.y, n0 = nb * 128;

  f32x4 acc[2][8];
#pragma unroll
  for (int i = 0; i < 2; ++i)
#pragma unroll
    for (int j = 0; j < 8; ++j) acc[i][j] = (f32x4){0.f, 0.f, 0.f, 0.f};

  for (int k0 = 0; k0 < 2048; k0 += 64) {
#pragma unroll
    for (int i = 0; i < 4; ++i) {
      int c = i * 256 + tid;
      int row = c >> 3, slot = c & 7;        // 8 x 16B chunks per 128B row
      gl_lds16(xbf + ((size_t)(m0 + row) * 2048 + k0 + ((slot ^ (row & 7)) << 3)),
               &As[c << 3]);
      gl_lds16(wt + ((size_t)(n0 + row) * 2048 + k0 + ((slot ^ (row & 7)) << 3)),
               &Bs[c << 3]);
    }
    __syncthreads();
#pragma unroll
    for (int kk = 0; kk < 2; ++kk) {
      bf16x8 av[2], bv[8];
#pragma unroll
      for (int mf = 0; mf < 2; ++mf) {
        int r = w * 32 + mf * 16 + ln;
        int cb = (kk * 64 + (g << 4)) ^ ((r & 7) << 4);
        av[mf] = *(const bf16x8*)&As[r * 64 + (cb >> 1)];
      }
#pragma unroll
      for (int nf = 0; nf < 8; ++nf) {
        int r = nf * 16 + ln;
        int cb = (kk * 64 + (g << 4)) ^ ((r & 7) << 4);
        bv[nf] = *(const bf16x8*)&Bs[r * 64 + (cb >> 1)];
      }
#pragma unroll
      for (int mf = 0; mf < 2; ++mf)
#pragma unroll
        for (int nf = 0; nf < 8; ++nf)
          acc[mf][nf] = mfma_bf16(av[mf], bv[nf], acc[mf][nf]);
    }
    __syncthreads();
  }

  // epilogue: bias, RoPE, scatter to q/k/v destinations
  const int p = nb >> 4, h = nb & 15;
  float bvv[8];
#pragma unroll
  for (int nf = 0; nf < 8; ++nf) bvv[nf] = bias[n0 + nf * 16 + ln];

  if (p == 2) {  // v: no rope
#pragma unroll
    for (int mf = 0; mf < 2; ++mf)
#pragma unroll
      for (int r = 0; r < 4; ++r) {
        int m = m0 + w * 32 + mf * 16 + g * 4 + r;
        int b = m >> 11, t = m & 2047;
        size_t base = ((size_t)(b * 16 + h) * 2048 + t) * 128;
#pragma unroll
        for (int nf = 0; nf < 8; ++nf)
          out_v[base + nf * 16 + ln] = acc[mf][nf][r] + bvv[nf];
      }
  } else {  // q (p==0) or k (p==1): rope
#pragma unroll
    for (int mf = 0; mf < 2; ++mf)
#pragma unroll
      for (int r = 0; r < 4; ++r) {
        int m = m0 + w * 32 + mf * 16 + g * 4 + r;
        int b = m >> 11, t = m & 2047;
        size_t base = ((size_t)(b * 16 + h) * 2048 + t) * 128;
#pragma unroll
        for (int nf = 0; nf < 4; ++nf) {
          int i = nf * 16 + ln;
          float cv = cost[t * 64 + i], sv = sint[t * 64 + i];
          float a = acc[mf][nf][r] + bvv[nf];
          float bq = acc[mf][nf + 4][r] + bvv[nf + 4];
          float lo = a * cv - bq * sv;
          float hi = bq * cv + a * sv;
          if (p == 0) {
            qbf[base + i] = f2bf(lo);
            qbf[base + i + 64] = f2bf(hi);
          } else {
            out_k[base + i] = lo;
            out_k[base + i + 64] = hi;
            kbf[base + i] = f2bf(lo);
            kbf[base + i + 64] = f2bf(hi);
          }
        }
      }
  }
}

// ---------------------------------------------------------------------------
// Flash attention: grid (T/64, B*H). 4 waves x 16 q-rows. KV tiles of 64.
// q/k bf16 [z][T][D]; vt bf16 [z][D][T]; out ybf [B*T][C] (transposed merge).
// ---------------------------------------------------------------------------
__global__ __launch_bounds__(256) void attn_kernel(
    const unsigned short* __restrict__ qbf, const unsigned short* __restrict__ kbf,
    const unsigned short* __restrict__ vtbf, unsigned short* __restrict__ ybf) {
  __shared__ __attribute__((aligned(16))) unsigned short Qs[64 * 128];
  __shared__ __attribute__((aligned(16))) unsigned short Ks[64 * 128];
  __shared__ __attribute__((aligned(16))) unsigned short Vts[128 * 64];
  __shared__ __attribute__((aligned(16))) unsigned short Ps[64 * 64];
  const int tid = threadIdx.x;
  const int w = tid >> 6, l = tid & 63, g = l >> 4, ln = l & 15;
  const int qb = blockIdx.x, z = blockIdx.y;
  const size_t zo = (size_t)z * 2048 * 128;

  // stage Q tile (64 rows x 128 d), swizzled
#pragma unroll
  for (int i = 0; i < 4; ++i) {
    int c = i * 256 + tid;
    int row = c >> 4, slot = c & 15;       // 16 x 16B chunks per 256B row
    gl_lds16(qbf + zo + (size_t)(qb * 64 + row) * 128 + ((slot ^ (row & 7)) << 3),
             &Qs[c << 3]);
  }

  f32x4 o[8];
#pragma unroll
  for (int i = 0; i < 8; ++i) o[i] = (f32x4){0.f, 0.f, 0.f, 0.f};
  float mrun[4], lrun[4];
#pragma unroll
  for (int r = 0; r < 4; ++r) { mrun[r] = -3e38f; lrun[r] = 0.f; }

  const int jmax = qb + 1;
  for (int j = 0; j < jmax; ++j) {
    const int kv0 = j * 64;
#pragma unroll
    for (int i = 0; i < 4; ++i) {
      int c = i * 256 + tid;
      int row = c >> 4, slot = c & 15;
      gl_lds16(kbf + zo + (size_t)(kv0 + row) * 128 + ((slot ^ (row & 7)) << 3),
               &Ks[c << 3]);
    }
#pragma unroll
    for (int i = 0; i < 4; ++i) {
      int c = i * 256 + tid;
      int d = c >> 3, slot = c & 7;        // 8 x 16B chunks per 128B row
      gl_lds16(vtbf + (size_t)z * 128 * 2048 + (size_t)d * 2048 + kv0 +
                   ((slot ^ (d & 7)) << 3),
               &Vts[c << 3]);
    }
    __syncthreads();

    // S = Q K^T (16q x 64kv per wave)
    f32x4 s[4];
#pragma unroll
    for (int i = 0; i < 4; ++i) s[i] = (f32x4){0.f, 0.f, 0.f, 0.f};
#pragma unroll
    for (int kk = 0; kk < 4; ++kk) {
      int qr = w * 16 + ln;
      bf16x8 qv = *(const bf16x8*)
          &Qs[qr * 128 + (((kk * 64 + (g << 4)) ^ ((qr & 7) << 4)) >> 1)];
#pragma unroll
      for (int nf = 0; nf < 4; ++nf) {
        int kr = nf * 16 + ln;
        bf16x8 kv = *(const bf16x8*)
            &Ks[kr * 128 + (((kk * 64 + (g << 4)) ^ ((kr & 7) << 4)) >> 1)];
        s[nf] = mfma_bf16(qv, kv, s[nf]);
      }
    }

    // online softmax (rows owned per-lane: q = g*4 + r, replicated over ln)
    const float sc = 0.08838834764831845f;  // 1/sqrt(128)
#pragma unroll
    for (int r = 0; r < 4; ++r) {
      const int qg = qb * 64 + w * 16 + g * 4 + r;
      float mx = -3e38f;
#pragma unroll
      for (int nf = 0; nf < 4; ++nf) {
        float v = s[nf][r] * sc;
        if (kv0 + nf * 16 + ln > qg) v = -3e38f;  // causal mask
        s[nf][r] = v;
        mx = fmaxf(mx, v);
      }
      mx = fmaxf(mx, __shfl_xor(mx, 1));
      mx = fmaxf(mx, __shfl_xor(mx, 2));
      mx = fmaxf(mx, __shfl_xor(mx, 4));
      mx = fmaxf(mx, __shfl_xor(mx, 8));
      float mnew = fmaxf(mrun[r], mx);
      float alpha = __expf(mrun[r] - mnew);
      float rs = 0.f;
#pragma unroll
      for (int nf = 0; nf < 4; ++nf) {
        float pv = __expf(s[nf][r] - mnew);
        s[nf][r] = pv;
        rs += pv;
      }
      rs += __shfl_xor(rs, 1);
      rs += __shfl_xor(rs, 2);
      rs += __shfl_xor(rs, 4);
      rs += __shfl_xor(rs, 8);
      lrun[r] = lrun[r] * alpha + rs;
      mrun[r] = mnew;
#pragma unroll
      for (int nf2 = 0; nf2 < 8; ++nf2) o[nf2][r] *= alpha;
    }

    // P -> LDS (own-wave rows only; swizzled), then O += P V
#pragma unroll
    for (int r = 0; r < 4; ++r) {
      int qrow = w * 16 + g * 4 + r;
#pragma unroll
      for (int nf = 0; nf < 4; ++nf) {
        int byte = ((nf * 16 + ln) << 1) ^ ((qrow & 7) << 4);
        Ps[qrow * 64 + (byte >> 1)] = f2bf(s[nf][r]);
      }
    }
#pragma unroll
    for (int kk2 = 0; kk2 < 2; ++kk2) {
      int pr = w * 16 + ln;
      bf16x8 pa = *(const bf16x8*)
          &Ps[pr * 64 + (((kk2 * 64 + (g << 4)) ^ ((pr & 7) << 4)) >> 1)];
#pragma unroll
      for (int nf2 = 0; nf2 < 8; ++nf2) {
        int dr = nf2 * 16 + ln;
        bf16x8 vv = *(const bf16x8*)
            &Vts[dr * 64 + (((kk2 * 64 + (g << 4)) ^ ((dr & 7) << 4)) >> 1)];
        o[nf2] = mfma_bf16(pa, vv, o[nf2]);
      }
    }
    __syncthreads();
  }

  // normalize + write y in [B*T][C] layout (col = h*128 + d)
  const int b = z >> 4, h = z & 15;
#pragma unroll
  for (int r = 0; r < 4; ++r) {
    float inv = 1.f / lrun[r];
    int t = qb * 64 + w * 16 + g * 4 + r;
    size_t rb = ((size_t)b * 2048 + t) * 2048 + h * 128;
#pragma unroll
    for (int nf = 0; nf < 8; ++nf)
      ybf[rb + nf * 16 + ln] = f2bf(o[nf][r] * inv);
  }
}

// ---------------------------------------------------------------------------
// GEMM2: out = y @ W_proj + b_proj (f32 out to d_out[0:16.7M])
// ---------------------------------------------------------------------------
__global__ __launch_bounds__(256) void gemm_proj_kernel(
    const unsigned short* __restrict__ ybf, const unsigned short* __restrict__ wpt,
    const float* __restrict__ bias, float* __restrict__ out) {
  __shared__ __attribute__((aligned(16))) unsigned short As[128 * 64];
  __shared__ __attribute__((aligned(16))) unsigned short Bs[128 * 64];
  const int tid = threadIdx.x;
  const int w = tid >> 6, l = tid & 63, g = l >> 4, ln = l & 15;
  const int m0 = blockIdx.x * 128;
  const int n0 = blockIdx.y * 128;

  f32x4 acc[2][8];
#pragma unroll
  for (int i = 0; i < 2; ++i)
#pragma unroll
    for (int j = 0; j < 8; ++j) acc[i][j] = (f32x4){0.f, 0.f, 0.f, 0.f};

  for (int k0 = 0; k0 < 2048; k0 += 64) {
#pragma unroll
    for (int i = 0; i < 4; ++i) {
      int c = i * 256 + tid;
      int row = c >> 3, slot = c & 7;
      gl_lds16(ybf + ((size_t)(m0 + row) * 2048 + k0 + ((slot ^ (row & 7)) << 3)),
               &As[c << 3]);
      gl_lds16(wpt + ((size_t)(n0 + row) * 2048 + k0 + ((slot ^ (row & 7)) << 3)),
               &Bs[c << 3]);
    }
    __syncthreads();
#pragma unroll
    for (int kk = 0; kk < 2; ++kk) {
      bf16x8 av[2], bv[8];
#pragma unroll
      for (int mf = 0; mf < 2; ++mf) {
        int r = w * 32 + mf * 16 + ln;
        int cb = (kk * 64 + (g << 4)) ^ ((r & 7) << 4);
        av[mf] = *(const bf16x8*)&As[r * 64 + (cb >> 1)];
      }
#pragma unroll
      for (int nf = 0; nf < 8; ++nf) {
        int r = nf * 16 + ln;
        int cb = (kk * 64 + (g << 4)) ^ ((r & 7) << 4);
        bv[nf] = *(const bf16x8*)&Bs[r * 64 + (cb >> 1)];
      }
#pragma unroll
      for (int mf = 0; mf < 2; ++mf)
#pragma unroll
        for (int nf = 0; nf < 8; ++nf)
          acc[mf][nf] = mfma_bf16(av[mf], bv[nf], acc[mf][nf]);
    }
    __syncthreads();
  }

  float bvv[8];
#pragma unroll
  for (int nf = 0; nf < 8; ++nf) bvv[nf] = bias[n0 + nf * 16 + ln];
#pragma unroll
  for (int mf = 0; mf < 2; ++mf)
#pragma unroll
    for (int r = 0; r < 4; ++r) {
      int m = m0 + w * 32 + mf * 16 + g * 4 + r;
      size_t rb = (size_t)m * 2048 + n0;
#pragma unroll
      for (int nf = 0; nf < 8; ++nf)
        out[rb + nf * 16 + ln] = acc[mf][nf][r] + bvv[nf];
    }
}

// ---------------------------------------------------------------------------
// Launch
// ---------------------------------------------------------------------------
extern "C" void kernel_launch(void* const* d_in, const int* in_sizes, int n_in,
                              void* d_out, int out_size, void* d_ws, size_t ws_size,
                              hipStream_t stream) {
  (void)in_sizes; (void)n_in; (void)out_size; (void)ws_size;
  const float* x      = (const float*)d_in[0];
  const float* W_attn = (const float*)d_in[1];
  const float* b_attn = (const float*)d_in[2];
  const float* W_proj = (const float*)d_in[3];
  const float* b_proj = (const float*)d_in[4];

  float* out   = (float*)d_out;                 // [8192][2048]
  float* out_k = out + 16777216;                // [64][2048][128]
  float* out_v = out + 33554432;                // [64][2048][128]

  char* ws = (char*)d_ws;
  unsigned short* q_bf  = (unsigned short*)(ws + 0);           // 33.5 MB
  unsigned short* k_bf  = (unsigned short*)(ws + 33554432);    // 33.5 MB
  unsigned short* vt_bf = (unsigned short*)(ws + 67108864);    // 33.5 MB
  unsigned short* x_bf  = (unsigned short*)(ws + 100663296);   // 33.5 MB (reused as y2d)
  unsigned short* y2d   = x_bf;                                // alias: x_bf dead after GEMM1
  unsigned short* wt    = (unsigned short*)(ws + 134217728);   // 25.2 MB
  unsigned short* wpt   = (unsigned short*)(ws + 159383552);   // 8.4 MB
  float* cos_t = (float*)(ws + 167772160);                     // 0.5 MB
  float* sin_t = (float*)(ws + 168296448);                     // 0.5 MB

  rope_table_kernel<<<512, 256, 0, stream>>>(cos_t, sin_t);
  conv_bf16_kernel<<<2048, 256, 0, stream>>>(x, x_bf, 16777216 / 4);
  transpose_conv_kernel<<<dim3(6144 / 64, 2048 / 64), 256, 0, stream>>>(W_attn, wt, 2048, 6144);
  transpose_conv_kernel<<<dim3(2048 / 64, 2048 / 64), 256, 0, stream>>>(W_proj, wpt, 2048, 2048);
  gemm_qkv_kernel<<<dim3(64, 48), 256, 0, stream>>>(x_bf, wt, b_attn, cos_t, sin_t,
                                                    out_k, out_v, q_bf, k_bf);
  vtrans_kernel<<<dim3(32, 2, 64), 256, 0, stream>>>(out_v, vt_bf);
  attn_kernel<<<dim3(32, 64), 256, 0, stream>>>(q_bf, k_bf, vt_bf, y2d);
  gemm_proj_kernel<<<dim3(64, 16), 256, 0, stream>>>(y2d, wpt, b_proj, out);
}